// Round 9
// baseline (6278.628 us; speedup 1.0000x reference)
//
#include <hip/hip_runtime.h>
#include <hip/hip_bf16.h>
#include <math.h>

// Problem dims
#define PP 400
#define QQ 30
#define BB 32
#define EE 300
#define HH 300
#define FF 300
#define AA 30
#define LL 2

typedef unsigned short ushort_t;
typedef unsigned int uint_t;
typedef __attribute__((ext_vector_type(8))) short short8;
typedef __attribute__((ext_vector_type(16))) float floatx16;
typedef __attribute__((ext_vector_type(4))) uint_t uintx4;

__device__ __forceinline__ uint_t f2bf(float f) {
    uint_t u = __float_as_uint(f);
    return (u + 0x7fffu + ((u >> 16) & 1u)) >> 16;
}
__device__ __forceinline__ float bf2f(ushort_t v) {
    return __uint_as_float(((uint_t)v) << 16);
}

// ---------------------------------------------------------------------------
// Embedding gather -> bf16 with K padded 300->304 (pad zeroed)
__global__ void gather_embed_bf(const int* __restrict__ tok,
                                const float* __restrict__ embed,
                                ushort_t* __restrict__ out, int n_tok) {
    int i = blockIdx.x * blockDim.x + threadIdx.x;
    int n = n_tok * 304;
    if (i >= n) return;
    int row = i / 304, e = i - row * 304;
    out[i] = (e < EE) ? (ushort_t)f2bf(embed[(size_t)tok[row] * EE + e]) : 0;
}

// fp32 [R][K] -> bf16 [R][KP], zero pad
__global__ void convert_pad_bf16(const float* __restrict__ src,
                                 ushort_t* __restrict__ dst,
                                 int R, int K, int KP) {
    int i = blockIdx.x * blockDim.x + threadIdx.x;
    if (i >= R * KP) return;
    int r = i / KP, k = i - r * KP;
    dst[i] = (k < K) ? (ushort_t)f2bf(src[(size_t)r * K + k]) : 0;
}

// ---------------------------------------------------------------------------
// MFMA bf16 GEMM: C[M,N] = A[M,KP] @ B[N,KP]^T + bias[N], optional relu.
// 64x64 tile, 256 threads = 4 waves, one 32x32x16 MFMA per wave per K-chunk.
__global__ __launch_bounds__(256) void gemm_bf16_nt(
        const ushort_t* __restrict__ A, const ushort_t* __restrict__ B,
        const float* __restrict__ bias, float* __restrict__ C,
        int M, int N, int KP, int relu) {
    __shared__ __align__(16) ushort_t As[64][16];
    __shared__ __align__(16) ushort_t Bs[64][16];
    int tid = threadIdx.x;
    int m0 = blockIdx.y * 64, n0 = blockIdx.x * 64;
    int lane = tid & 63, wv = tid >> 6;
    int wm = wv >> 1, wn = wv & 1;
    int tile = tid >> 7;
    int trow = (tid & 127) >> 1;
    int tkof = (tid & 1) * 8;
    floatx16 acc;
    #pragma unroll
    for (int r = 0; r < 16; r++) acc[r] = 0.f;

    for (int k0 = 0; k0 < KP; k0 += 16) {
        short8 v;
        if (tile == 0) {
            v = *(const short8*)(A + (size_t)(m0 + trow) * KP + k0 + tkof);
        } else {
            int br = n0 + trow;
            if (br < N)
                v = *(const short8*)(B + (size_t)br * KP + k0 + tkof);
            else
                v = short8(0);
        }
        __syncthreads();
        if (tile == 0) *(short8*)&As[trow][tkof] = v;
        else           *(short8*)&Bs[trow][tkof] = v;
        __syncthreads();
        short8 af = *(const short8*)&As[wm * 32 + (lane & 31)][(lane >> 5) * 8];
        short8 bf = *(const short8*)&Bs[wn * 32 + (lane & 31)][(lane >> 5) * 8];
        acc = __builtin_amdgcn_mfma_f32_32x32x16_bf16(af, bf, acc, 0, 0, 0);
    }
    int col = n0 + wn * 32 + (lane & 31);
    if (col < N) {
        float bv = bias[col];
        int rbase = m0 + wm * 32 + 4 * (lane >> 5);
        #pragma unroll
        for (int r = 0; r < 16; r++) {
            int row = rbase + (r & 3) + 8 * (r >> 2);
            float v = acc[r] + bv;
            if (relu) v = fmaxf(v, 0.f);
            C[(size_t)row * N + col] = v;
        }
    }
}

// ---------------------------------------------------------------------------
// scores + softmax over q per (p,b)
__global__ void scores_softmax(const float* __restrict__ ffp,
                               const float* __restrict__ ffq,
                               const float* __restrict__ p_mask,
                               const float* __restrict__ q_mask,
                               float* __restrict__ weights) {
    int blk = blockIdx.x;          // p*BB + b
    int p = blk / BB, b = blk - p * BB;
    __shared__ float fp[FF];
    __shared__ float sq[QQ];
    for (int f = threadIdx.x; f < FF; f += blockDim.x)
        fp[f] = ffp[(size_t)(p * BB + b) * FF + f];
    __syncthreads();
    int q = threadIdx.x;
    if (q < QQ) {
        const float* fq = ffq + (size_t)(q * BB + b) * FF;
        float s = 0.f;
        for (int f = 0; f < FF; f++) s += fp[f] * fq[f];
        s *= p_mask[p * BB + b] * q_mask[q * BB + b];
        sq[q] = s;
    }
    __syncthreads();
    if (q < QQ) {
        float m = -INFINITY;
        for (int k = 0; k < QQ; k++) m = fmaxf(m, sq[k]);
        float sum = 0.f;
        for (int k = 0; k < QQ; k++) sum += expf(sq[k] - m);
        weights[(size_t)b * PP * QQ + p * QQ + q] = expf(sq[q] - m) / sum;
    }
}

// ---------------------------------------------------------------------------
// x0BF[p][b][0:300] = p_embBF; [300:600] = bf16(sum_q w*q_emb). Stride 608.
__global__ void align_concat_bf(const float* __restrict__ weights,
                                const ushort_t* __restrict__ q_embBF,
                                const ushort_t* __restrict__ p_embBF,
                                ushort_t* __restrict__ x0BF) {
    int blk = blockIdx.x;          // p*BB + b
    int p = blk / BB, b = blk - p * BB;
    __shared__ float w[QQ];
    if (threadIdx.x < QQ)
        w[threadIdx.x] = weights[(size_t)b * PP * QQ + p * QQ + threadIdx.x];
    __syncthreads();
    size_t obase = (size_t)(p * BB + b) * 608;
    for (int e = threadIdx.x; e < EE; e += blockDim.x) {
        float acc = 0.f;
        for (int q = 0; q < QQ; q++)
            acc += w[q] * bf2f(q_embBF[(size_t)(q * BB + b) * 304 + e]);
        x0BF[obase + e] = p_embBF[(size_t)(p * BB + b) * 304 + e];
        x0BF[obase + EE + e] = (ushort_t)f2bf(acc);
    }
}

// ---------------------------------------------------------------------------
// w_hh fp32 [4][900][300] -> bf16 (RNE) same layout (GRU A-fragments)
__global__ void convert_whh_bf16(const float* __restrict__ w,
                                 ushort_t* __restrict__ o) {
    int i = blockIdx.x * blockDim.x + threadIdx.x;
    if (i >= 4 * 900 * 300) return;
    o[i] = (ushort_t)f2bf(w[i]);
}

// ---------------------------------------------------------------------------
// Persistent BiGRU layer (R9): 2 blocks per dir, grid = 4 x 512 threads.
// Block bi owns j-slice [bi*150, bi*150+150) for all 32 batches: 450 weight
// rows as 15 MFMA tiles; wave wv holds tiles 2wv,2wv+1 (rows 64wv..64wv+63)
// RESIDENT in VGPRs (152 regs). Both tiles share one ds_read_b128 B-fragment
// (same h) -> LDS traffic halved. b_hh is FOLDED into K: sh2 col 300 = 1.0,
// weight chunk 18 col 300 = b_hh row. Gate thread t<400 owns packets
// {t, t+400} (12 h): gates -> publish 16B tagged packets from registers for
// the OTHER block; own half written straight to LDS (no LLC). Consumers poll
// only the other block's 800 packets (<=2/thread). 8-slot ring, lag <= 1.
#define RSLOT 8
#define HBUF_DWORDS (2 * RSLOT * 1600 * 4)

__global__ __launch_bounds__(512, 1) void gru_layer(
        const float* __restrict__ xp_all, // [2 dir][400][32][900]
        const ushort_t* __restrict__ wbf, // [2 dir][900][300] bf16
        const float* __restrict__ bhh,    // [2 dir][900]
        uint_t* __restrict__ hbuf,        // packet ring
        int layer,
        ushort_t* __restrict__ out) {     // [400][32][608] bf16
    int dir = blockIdx.x >> 1;
    int bi  = blockIdx.x & 1;
    int j0  = bi * 150;
    const float* xp = xp_all + (size_t)dir * (400 * 32 * 900);
    int tid = threadIdx.x;
    int lane = tid & 63;
    int wv = tid >> 6;                 // 0..7
    uint_t* hb_dir = hbuf + (size_t)dir * (RSLOT * 1600 * 4);

    __shared__ __align__(16) ushort_t sh2[32][312]; // h bf16 [b][k], k 304 used
    __shared__ float sgh[450][33];    // gh f32 [block row][batch]

    // init: zeros + bias-constant 1.0 at col 300
    for (int i = tid; i < 32 * 156; i += 512)
        ((uint_t*)sh2)[i] = ((i % 156) == 150) ? 0x00003F80u : 0u;

    // A-fragments resident: 2 tiles per wave; chunk 18 col 300 = b_hh
    short8 afrag[2][19];
    {
        int m = lane & 31, half = lane >> 5;
        #pragma unroll
        for (int th = 0; th < 2; th++) {
            int grow = wv * 64 + th * 32 + m;
            if (grow < 450) {
                int gate = grow / 150, jl = grow - gate * 150;
                const ushort_t* wrow = wbf + (size_t)dir * 270000
                                       + (size_t)(gate * 300 + j0 + jl) * 300;
                ushort_t bb = (ushort_t)f2bf(bhh[dir * 900 + gate * 300 + j0 + jl]);
                for (int c = 0; c < 19; c++) {
                    int k0 = c * 16 + half * 8;
                    short8 f;
                    #pragma unroll
                    for (int e = 0; e < 8; e++) {
                        int k = k0 + e;
                        f[e] = (short)(k < 300 ? wrow[k]
                                       : (k == 300 ? bb : (ushort_t)0));
                    }
                    afrag[th][c] = f;
                }
            } else {
                for (int c = 0; c < 19; c++) afrag[th][c] = short8(0);
            }
        }
    }
    int otherbase = (1 - bi) * 800;
    // gate ownership: packets p0=tid, p1=tid+400 (tid<400)
    int g_b0 = tid / 25, g_q0 = tid - (tid / 25) * 25;
    int t1 = tid + 400;
    int g_b1 = t1 / 25, g_q1 = t1 - (t1 / 25) * 25;
    float hprev[12] = {0.f, 0.f, 0.f, 0.f, 0.f, 0.f,
                       0.f, 0.f, 0.f, 0.f, 0.f, 0.f};
    // poll: P0 = tid (always < 800), P1 = tid + 512 (if tid < 288)
    int P0 = tid, P1 = tid + 512;
    int b_P0 = P0 / 25, q_P0 = P0 - b_P0 * 25;
    int dst0 = b_P0 * 156 + (1 - bi) * 75 + 3 * q_P0;
    int b_P1 = P1 / 25, q_P1 = P1 - b_P1 * 25;
    int dst1 = b_P1 * 156 + (1 - bi) * 75 + 3 * q_P1;
    int has1 = (tid < 288);
    __syncthreads();

    for (int s = 0; s < PP; s++) {
        int te = dir ? (PP - 1 - s) : s;
        // group-0 xp prefetch (overlaps the poll)
        float xA[18];
        if (tid < 400) {
            const float* base = xp + ((size_t)te * 32 + g_b0) * 900
                                + j0 + g_q0 * 6;
            #pragma unroll
            for (int u = 0; u < 3; u++) {
                *(float2*)&xA[2 * u]      = *(const float2*)(base + 2 * u);
                *(float2*)&xA[6 + 2 * u]  = *(const float2*)(base + 300 + 2 * u);
                *(float2*)&xA[12 + 2 * u] = *(const float2*)(base + 600 + 2 * u);
            }
        }
        // poll the other block's packets for h(s)
        if (s > 0) {
            uint_t want = (uint_t)(layer * 1024 + s);
            const uint_t* base = hb_dir + (size_t)(s & 7) * (1600 * 4);
            uintx4 v0, v1;
            int pend = 1 | (has1 << 1);
            uint_t* shdw = (uint_t*)sh2;
            const uint_t* a0 = base + (size_t)(otherbase + P0) * 4;
            const uint_t* a1 = base + (size_t)(otherbase + ((tid < 288) ? P1 : P0)) * 4;
            while (pend) {
                if (pend & 1)
                    asm volatile("global_load_dwordx4 %0, %1, off sc0 sc1"
                                 : "=&v"(v0) : "v"(a0) : "memory");
                if (pend & 2)
                    asm volatile("global_load_dwordx4 %0, %1, off sc0 sc1"
                                 : "=&v"(v1) : "v"(a1) : "memory");
                asm volatile("s_waitcnt vmcnt(0)" ::: "memory");
                if ((pend & 1) && v0.w == want) {
                    pend &= ~1;
                    shdw[dst0 + 0] = v0.x; shdw[dst0 + 1] = v0.y;
                    shdw[dst0 + 2] = v0.z;
                }
                if ((pend & 2) && v1.w == want) {
                    pend &= ~2;
                    shdw[dst1 + 0] = v1.x; shdw[dst1 + 1] = v1.y;
                    shdw[dst1 + 2] = v1.z;
                }
            }
        }
        __syncthreads();                       // B1: sh2 complete
        // MFMA: one B-fragment feeds both resident tiles
        {
            floatx16 a0, a1;
            #pragma unroll
            for (int r = 0; r < 16; r++) { a0[r] = 0.f; a1[r] = 0.f; }
            int n = lane & 31, half = lane >> 5;
            #pragma unroll
            for (int c = 0; c < 19; c++) {
                short8 bf = *(const short8*)&sh2[n][c * 16 + half * 8];
                a0 = __builtin_amdgcn_mfma_f32_32x32x16_bf16(
                    afrag[0][c], bf, a0, 0, 0, 0);
                a1 = __builtin_amdgcn_mfma_f32_32x32x16_bf16(
                    afrag[1][c], bf, a1, 0, 0, 0);
            }
            int col = lane & 31, rbase = 4 * (lane >> 5);
            #pragma unroll
            for (int r = 0; r < 16; r++) {
                int row = (r & 3) + 8 * (r >> 2) + rbase;
                int gr0 = wv * 64 + row;
                if (gr0 < 450) sgh[gr0][col] = a0[r];
                int gr1 = wv * 64 + 32 + row;
                if (gr1 < 450) sgh[gr1][col] = a1[r];
            }
        }
        __syncthreads();                       // B2: sgh complete
        // gates (2 packet-groups), publish from regs, own half to LDS
        if (tid < 400) {
            uint_t want1 = (uint_t)(layer * 1024 + s + 1);
            uint_t* slot = hb_dir + (size_t)((s + 1) & 7) * (1600 * 4);
            // ---- group 0 ----
            {
                float houts[6];
                #pragma unroll
                for (int i = 0; i < 6; i++) {
                    int jl = g_q0 * 6 + i;
                    float r = 1.f / (1.f + expf(-(xA[i] + sgh[jl][g_b0])));
                    float z = 1.f / (1.f + expf(-(xA[6 + i] + sgh[150 + jl][g_b0])));
                    float n = tanhf(xA[12 + i] + r * sgh[300 + jl][g_b0]);
                    float h = (1.f - z) * n + z * hprev[i];
                    hprev[i] = h;
                    houts[i] = h;
                }
                uintx4 pkt;
                pkt.x = f2bf(houts[0]) | (f2bf(houts[1]) << 16);
                pkt.y = f2bf(houts[2]) | (f2bf(houts[3]) << 16);
                pkt.z = f2bf(houts[4]) | (f2bf(houts[5]) << 16);
                pkt.w = want1;
                uint_t* pa = slot + (size_t)(bi * 800 + tid) * 4;
                asm volatile("global_store_dwordx4 %0, %1, off sc0 sc1"
                             :: "v"(pa), "v"(pkt) : "memory");
                uint_t* shdw = (uint_t*)sh2;
                int od = g_b0 * 156 + bi * 75 + 3 * g_q0;
                shdw[od + 0] = pkt.x; shdw[od + 1] = pkt.y; shdw[od + 2] = pkt.z;
                uint_t* ob = (uint_t*)(out + ((size_t)te * 32 + g_b0) * 608
                                       + dir * 300 + j0 + g_q0 * 6);
                ob[0] = pkt.x; ob[1] = pkt.y; ob[2] = pkt.z;
            }
            // ---- group 1 ----
            {
                float xB[18];
                const float* base = xp + ((size_t)te * 32 + g_b1) * 900
                                    + j0 + g_q1 * 6;
                #pragma unroll
                for (int u = 0; u < 3; u++) {
                    *(float2*)&xB[2 * u]      = *(const float2*)(base + 2 * u);
                    *(float2*)&xB[6 + 2 * u]  = *(const float2*)(base + 300 + 2 * u);
                    *(float2*)&xB[12 + 2 * u] = *(const float2*)(base + 600 + 2 * u);
                }
                float houts[6];
                #pragma unroll
                for (int i = 0; i < 6; i++) {
                    int jl = g_q1 * 6 + i;
                    float r = 1.f / (1.f + expf(-(xB[i] + sgh[jl][g_b1])));
                    float z = 1.f / (1.f + expf(-(xB[6 + i] + sgh[150 + jl][g_b1])));
                    float n = tanhf(xB[12 + i] + r * sgh[300 + jl][g_b1]);
                    float h = (1.f - z) * n + z * hprev[6 + i];
                    hprev[6 + i] = h;
                    houts[i] = h;
                }
                uintx4 pkt;
                pkt.x = f2bf(houts[0]) | (f2bf(houts[1]) << 16);
                pkt.y = f2bf(houts[2]) | (f2bf(houts[3]) << 16);
                pkt.z = f2bf(houts[4]) | (f2bf(houts[5]) << 16);
                pkt.w = want1;
                uint_t* pa = slot + (size_t)(bi * 800 + t1) * 4;
                asm volatile("global_store_dwordx4 %0, %1, off sc0 sc1"
                             :: "v"(pa), "v"(pkt) : "memory");
                uint_t* shdw = (uint_t*)sh2;
                int od = g_b1 * 156 + bi * 75 + 3 * g_q1;
                shdw[od + 0] = pkt.x; shdw[od + 1] = pkt.y; shdw[od + 2] = pkt.z;
                uint_t* ob = (uint_t*)(out + ((size_t)te * 32 + g_b1) * 608
                                       + dir * 300 + j0 + g_q1 * 6);
                ob[0] = pkt.x; ob[1] = pkt.y; ob[2] = pkt.z;
            }
        }
    }
}

// ---------------------------------------------------------------------------
__global__ void span_score(const float* __restrict__ stt,
                           const float* __restrict__ endv,
                           const float* __restrict__ w_a,
                           const int* __restrict__ p_lens,
                           float* __restrict__ final_) {
    int blk = blockIdx.x;          // p*BB + b
    int p = blk / BB, b = blk - p * BB;
    __shared__ float ss[FF];
    __shared__ float wa[FF];
    for (int f = threadIdx.x; f < FF; f += blockDim.x) {
        ss[f] = stt[(size_t)(p * BB + b) * FF + f];
        wa[f] = w_a[f];
    }
    __syncthreads();
    int lane = threadIdx.x & 63, wv = threadIdx.x >> 6;
    int plen = p_lens[b];
    for (int j = wv; j < AA; j += 2) {
        float acc = 0.f;
        int pe = p + j;
        if (pe < PP) {
            const float* ev = endv + (size_t)(pe * BB + b) * FF;
            for (int f = lane; f < FF; f += 64)
                acc += fmaxf(ss[f] + ev[f], 0.f) * wa[f];
        } else {
            for (int f = lane; f < FF; f += 64)
                acc += fmaxf(ss[f], 0.f) * wa[f];
        }
        #pragma unroll
        for (int off = 32; off; off >>= 1) acc += __shfl_down(acc, off);
        if (lane == 0) {
            float v = (pe < plen) ? acc : 0.f;
            final_[(size_t)b * (PP * AA) + p * AA + j] = v;
        }
    }
}

// ---------------------------------------------------------------------------
__global__ void log_softmax_rows(float* __restrict__ out,
                                 const float* __restrict__ final_, int n) {
    int b = blockIdx.x;
    const float* row = final_ + (size_t)b * n;
    __shared__ float red[256];
    float m = -INFINITY;
    for (int i = threadIdx.x; i < n; i += 256) m = fmaxf(m, row[i]);
    red[threadIdx.x] = m;
    __syncthreads();
    for (int s = 128; s; s >>= 1) {
        if (threadIdx.x < s) red[threadIdx.x] = fmaxf(red[threadIdx.x], red[threadIdx.x + s]);
        __syncthreads();
    }
    m = red[0];
    __syncthreads();
    float sum = 0.f;
    for (int i = threadIdx.x; i < n; i += 256) sum += expf(row[i] - m);
    red[threadIdx.x] = sum;
    __syncthreads();
    for (int s = 128; s; s >>= 1) {
        if (threadIdx.x < s) red[threadIdx.x] += red[threadIdx.x + s];
        __syncthreads();
    }
    float lse = m + logf(red[0]);
    for (int i = threadIdx.x; i < n; i += 256) out[(size_t)b * n + i] = row[i] - lse;
}

// ---------------------------------------------------------------------------
extern "C" void kernel_launch(void* const* d_in, const int* in_sizes, int n_in,
                              void* d_out, int out_size, void* d_ws, size_t ws_size,
                              hipStream_t stream) {
    (void)in_sizes; (void)n_in; (void)out_size; (void)ws_size;
    const int*   p_tok  = (const int*)d_in[0];
    const int*   q_tok  = (const int*)d_in[1];
    const float* p_mask = (const float*)d_in[2];
    const float* q_mask = (const float*)d_in[3];
    const int*   p_lens = (const int*)d_in[4];
    const float* embed   = (const float*)d_in[6];
    const float* w_align = (const float*)d_in[7];
    const float* b_align = (const float*)d_in[8];
    const float* w_ih    = (const float*)d_in[9];    // [2,2,900,600]
    const float* w_hh    = (const float*)d_in[10];   // [2,2,900,300]
    const float* b_ih    = (const float*)d_in[11];   // [2,2,900]
    const float* b_hh    = (const float*)d_in[12];   // [2,2,900]
    const float* w_stt   = (const float*)d_in[13];
    const float* b_stt   = (const float*)d_in[14];
    const float* w_end   = (const float*)d_in[15];
    const float* b_end   = (const float*)d_in[16];
    const float* w_a     = (const float*)d_in[17];
    float* out = (float*)d_out;
    float* ws = (float*)d_ws;

    // Workspace layout (float units; offsets multiples of 4 -> 16B align)
    size_t off = 0;
    ushort_t* p_embBF = (ushort_t*)(ws + off); off += 1945600;  // 12800x304
    ushort_t* q_embBF = (ushort_t*)(ws + off); off += 145920;   // 960x304
    float* ff_p  = ws + off;  off += (size_t)12800 * 300;
    float* ff_q  = ws + off;  off += (size_t)960 * 300;
    float* scores= ws + off;  off += (size_t)BB * PP * QQ;
    ushort_t* x0BF = (ushort_t*)(ws + off); off += 3891200;     // 12800x608
    ushort_t* x1BF = (ushort_t*)(ws + off); off += 3891200;     // 12800x608
    float* xp_f  = ws + off;  off += (size_t)400 * 32 * 900;
    float* xp_b  = ws + off;  off += (size_t)400 * 32 * 900;
    ushort_t* wihBF   = (ushort_t*)(ws + off); off += 1094400;  // 4x900x608
    ushort_t* walignBF= (ushort_t*)(ws + off); off += 45600;    // 300x304
    ushort_t* wsttBF  = (ushort_t*)(ws + off); off += 91200;    // 300x608
    ushort_t* wendBF  = (ushort_t*)(ws + off); off += 91200;    // 300x608
    ushort_t* whhBF   = (ushort_t*)(ws + off); off += 540000;   // 4x900x300
    uint_t* hbuf = (uint_t*)(ws + off); off += HBUF_DWORDS;
    float* sttb  = xp_f;                        // alias (xp dead by then)
    float* endb  = xp_f + (size_t)12800 * 300;
    float* finalb= scores;

    const int M = PP * BB;      // 12800
    const int Mq = QQ * BB;     // 960

    // weight conversions (bf16, K padded)
    convert_whh_bf16<<<(4 * 900 * 300 + 255) / 256, 256, 0, stream>>>(w_hh, whhBF);
    for (int ld = 0; ld < 4; ld++)
        convert_pad_bf16<<<(900 * 608 + 255) / 256, 256, 0, stream>>>(
            w_ih + (size_t)ld * 900 * 600, wihBF + (size_t)ld * 900 * 608,
            900, 600, 608);
    convert_pad_bf16<<<(300 * 304 + 255) / 256, 256, 0, stream>>>(
        w_align, walignBF, 300, 300, 304);
    convert_pad_bf16<<<(300 * 608 + 255) / 256, 256, 0, stream>>>(
        w_stt, wsttBF, 300, 600, 608);
    convert_pad_bf16<<<(300 * 608 + 255) / 256, 256, 0, stream>>>(
        w_end, wendBF, 300, 600, 608);

    // zero x0BF/x1BF (pads must be 0 for the K-padded GEMMs)
    hipMemsetAsync(x0BF, 0, (size_t)12800 * 608 * 2, stream);
    hipMemsetAsync(x1BF, 0, (size_t)12800 * 608 * 2, stream);

    // 1. embedding gathers (bf16, padded)
    gather_embed_bf<<<(M * 304 + 255) / 256, 256, 0, stream>>>(p_tok, embed, p_embBF, M);
    gather_embed_bf<<<(Mq * 304 + 255) / 256, 256, 0, stream>>>(q_tok, embed, q_embBF, Mq);

    // 2. aligned-attention projections (relu) — MFMA bf16
    gemm_bf16_nt<<<dim3(5, 200), 256, 0, stream>>>(
        p_embBF, walignBF, b_align, ff_p, M, 300, 304, 1);
    gemm_bf16_nt<<<dim3(5, 15), 256, 0, stream>>>(
        q_embBF, walignBF, b_align, ff_q, Mq, 300, 304, 1);

    // 3. scores + softmax over q
    scores_softmax<<<PP * BB, 64, 0, stream>>>(ff_p, ff_q, p_mask, q_mask, scores);

    // 4. q_align + concat -> x0BF (bf16, stride 608)
    align_concat_bf<<<PP * BB, 256, 0, stream>>>(scores, q_embBF, p_embBF, x0BF);

    // 5. BiGRU, 2 layers: MFMA xp GEMMs + persistent MFMA recurrence
    for (int l = 0; l < LL; l++) {
        const ushort_t* xin = (l == 0) ? x0BF : x1BF;
        ushort_t* xout = (l == 0) ? x1BF : x0BF;
        gemm_bf16_nt<<<dim3(15, 200), 256, 0, stream>>>(
            xin, wihBF + (size_t)(l * 2 + 0) * 900 * 608,
            b_ih + (l * 2 + 0) * 900, xp_f, M, 900, 608, 0);
        gemm_bf16_nt<<<dim3(15, 200), 256, 0, stream>>>(
            xin, wihBF + (size_t)(l * 2 + 1) * 900 * 608,
            b_ih + (l * 2 + 1) * 900, xp_b, M, 900, 608, 0);
        gru_layer<<<4, 512, 0, stream>>>(
            xp_f,
            whhBF + (size_t)l * 2 * 270000,
            b_hh + (size_t)l * 2 * 900,
            hbuf, l, xout);
    }

    // 6. stt / end projections (relu) from layer-2 output (x0BF)
    gemm_bf16_nt<<<dim3(5, 200), 256, 0, stream>>>(
        x0BF, wsttBF, b_stt, sttb, M, 300, 608, 1);
    gemm_bf16_nt<<<dim3(5, 200), 256, 0, stream>>>(
        x0BF, wendBF, b_end, endb, M, 300, 608, 1);

    // 7. span scores
    span_score<<<PP * BB, 128, 0, stream>>>(sttb, endb, w_a, p_lens, finalb);

    // 8. log-softmax rows -> out
    log_softmax_rows<<<BB, 256, 0, stream>>>(out, finalb, PP * AA);
}